// Round 5
// baseline (1957.448 us; speedup 1.0000x reference)
//
#include <hip/hip_runtime.h>
#include <hip/hip_cooperative_groups.h>

// Tree-GRU encoder, round 5: both the x-side and h-side become proper tiled
// MFMA GEMMs with block-level staged (coalesced, swizzled) LDS tiles.
//  - xg = Xc @ Wx^T precomputed per pass by a dense GEMM (no recurrence dep).
//  - level loop (cooperative) does h-side only: weights 48KB LDS-resident,
//    A = compact level slice staged per 256-row tile, 8 K-chunks of 64,
//    reg-double-buffered; TD stages parent rows via per-lane indexed source.
//  - sequential passes share one xg buffer: ws ~174 MB.
//
// ws layout:
//   wt    bf16 4x[1536][512]    6,291,456 B  (dtWx,dtUh,tdWx,tdUh transposed)
//   Xc    bf16 [NG][512]       33,554,432 B  (emb gathered in slot order)
//   xg    bf16 [NG][1536]     100,663,296 B  (per-pass x-gates, reused)
//   Hs    bf16 [NG][512]       33,554,432 B  (DT: children-sum; TD: hidden)
//   zrow  bf16 [512]                 1,024 B (stays zero)
//   sched/meta/gidx/pslot i32        ~0.4 MB

#define NL 256
#define NB 128
#define NH 512
#define NG (NB * NL)

typedef short short8 __attribute__((ext_vector_type(8)));
typedef float f32x4 __attribute__((ext_vector_type(4)));

__device__ __forceinline__ float bf2f(unsigned short u) {
  union { unsigned int i; float f; } c; c.i = ((unsigned int)u) << 16; return c.f;
}
__device__ __forceinline__ unsigned short f2bf(float f) {
  union { float f; unsigned int i; } c; c.f = f;
  return (unsigned short)((c.i + 0x7FFFu + ((c.i >> 16) & 1u)) >> 16);  // RNE
}
__device__ __forceinline__ short8 pk_bf16(f32x4 a, f32x4 b) {
  union { unsigned int u[4]; short8 s; } r;
  asm("v_cvt_pk_bf16_f32 %0, %1, %2" : "=v"(r.u[0]) : "v"(a[0]), "v"(a[1]));
  asm("v_cvt_pk_bf16_f32 %0, %1, %2" : "=v"(r.u[1]) : "v"(a[2]), "v"(a[3]));
  asm("v_cvt_pk_bf16_f32 %0, %1, %2" : "=v"(r.u[2]) : "v"(b[0]), "v"(b[1]));
  asm("v_cvt_pk_bf16_f32 %0, %1, %2" : "=v"(r.u[3]) : "v"(b[2]), "v"(b[3]));
  return r.s;
}
__device__ __forceinline__ void atom_pk_bf16(unsigned short* p, unsigned int ud) {
  asm volatile("global_atomic_pk_add_bf16 %0, %1, off" :: "v"((void*)p), "v"(ud) : "memory");
}

// ---- prep: 4 weight matrices [512][1536] f32 -> transposed [1536][512] bf16 ----
__global__ void prep_wt4(const float* __restrict__ w0, const float* __restrict__ w1,
                         const float* __restrict__ w2, const float* __restrict__ w3,
                         unsigned short* __restrict__ wt) {
  __shared__ float t[32][33];
  const float* w = blockIdx.z == 0 ? w0 : blockIdx.z == 1 ? w1 : blockIdx.z == 2 ? w2 : w3;
  unsigned short* dst = wt + (size_t)blockIdx.z * 1536 * 512;
  int n0 = blockIdx.x * 32, k0 = blockIdx.y * 32;
  int tx = threadIdx.x & 31, ty = threadIdx.x >> 5;
  #pragma unroll
  for (int i = 0; i < 4; ++i)
    t[ty + 8 * i][tx] = w[(size_t)(k0 + ty + 8 * i) * 1536 + n0 + tx];
  __syncthreads();
  #pragma unroll
  for (int i = 0; i < 4; ++i)
    dst[(size_t)(n0 + ty + 8 * i) * 512 + k0 + tx] = f2bf(t[tx][ty + 8 * i]);
}

// ---- prep: depths, level buckets, slots, parent slots (1 block, 256 thr) ----
__global__ void prep_sched(const int* __restrict__ td_pidx,
                           const float* __restrict__ td_pval,
                           int* __restrict__ sched, int* __restrict__ meta,
                           int* __restrict__ gidx, int* __restrict__ pslot) {
  __shared__ unsigned char dep[NB][NL];
  __shared__ unsigned short cnb[NB][256];
  __shared__ int cnt[256];
  __shared__ int off[257];
  __shared__ int dmax_s;
  const int tid = threadIdx.x;
  for (int j = tid; j < NB * 256; j += 256) ((unsigned short*)cnb)[j] = 0;
  if (tid == 0) dmax_s = 0;
  __syncthreads();
  if (tid < NB) {
    int b = tid, lmax = 0;
    for (int i = 0; i < NL; ++i) {
      float pv = td_pval[i * NB + b];
      int pi = td_pidx[i * NB + b];
      int d = (pv != 0.f) ? (int)dep[b][pi] + 1 : 0;   // head[i] < i
      dep[b][i] = (unsigned char)d;
      cnb[b][d]++;
      lmax = max(lmax, d);
    }
    atomicMax(&dmax_s, lmax);
  }
  __syncthreads();
  {
    int s = 0;
    for (int b = 0; b < NB; ++b) s += cnb[b][tid];
    cnt[tid] = s;
  }
  __syncthreads();
  if (tid == 0) {
    int s = 0;
    for (int d = 0; d < 256; ++d) { off[d] = s; s += cnt[d]; }
    off[256] = s;
  }
  __syncthreads();
  {
    int run = off[tid];
    for (int b = 0; b < NB; ++b) {
      int t = cnb[b][tid];
      cnb[b][tid] = (unsigned short)run;
      run += t;
    }
  }
  __syncthreads();
  if (tid < NB) {
    int b = tid;
    for (int i = 0; i < NL; ++i) {
      float pv = td_pval[i * NB + b];
      int pi = td_pidx[i * NB + b];
      int d = dep[b][i];
      int g = cnb[b][d]++;
      sched[g] = (b << 8) | i;
      gidx[b * NL + i] = g;
      pslot[g] = (pv != 0.f) ? gidx[b * NL + pi] : -1;
    }
  }
  if (tid == 0) meta[0] = dmax_s;
  __syncthreads();
  meta[1 + tid] = off[tid];
  meta[257 + tid] = cnt[tid];
}

// ---- prep: gather emb rows into slot order, f32 -> bf16 ----
__global__ void prep_xc(const float* __restrict__ emb, const int* __restrict__ sched,
                        unsigned short* __restrict__ Xc) {
  int g = blockIdx.x * 4 + (threadIdx.x >> 6);
  int lane = threadIdx.x & 63;
  int e = sched[g];
  int b = e >> 8, node = e & 255;
  const float* src = emb + ((size_t)node * NB + b) * 512 + lane * 8;
  f32x4 v0 = *(const f32x4*)src;
  f32x4 v1 = *(const f32x4*)(src + 4);
  *(short8*)(Xc + (size_t)g * 512 + lane * 8) = pk_bf16(v0, v1);
}

// ---- dense GEMM: xg[NG][1536] = Xc[NG][512] @ W[1536][512]^T (bf16) ----
// block 256 thr / 4 waves, tile 128x128, BK=64, reg-double-buffered staging
// into swizzled LDS [row][128B], slot' = slot ^ (row&7).
__launch_bounds__(256, 2)
__global__ void gemm_xg(const unsigned short* __restrict__ Xc,
                        const unsigned short* __restrict__ W,
                        unsigned short* __restrict__ xg) {
  __shared__ unsigned char lds[32768];
  const int tid = threadIdx.x;
  const int m0 = blockIdx.x * 128;
  const int n0 = blockIdx.y * 128;
  const int w = tid >> 6, l = tid & 63;
  const int lm = l & 15, kg = l >> 4;
  const int wr = (w & 1) * 64, wc = (w >> 1) * 64;
  const int srow = tid >> 3, sslot = tid & 7;
  const int dsw = ((sslot ^ (srow & 7)) << 4);
  const unsigned short* asrc = Xc + (size_t)(m0 + srow) * 512 + sslot * 8;
  const unsigned short* bsrc = W + (size_t)(n0 + srow) * 512 + sslot * 8;
  unsigned char* Ab = lds;
  unsigned char* Bb = lds + 16384;
  short8 ra[4], rb[4];
  #pragma unroll
  for (int i = 0; i < 4; ++i) {
    ra[i] = *(const short8*)(asrc + i * 16384);
    rb[i] = *(const short8*)(bsrc + i * 16384);
  }
  f32x4 acc[4][4];
  #pragma unroll
  for (int a = 0; a < 4; ++a)
    #pragma unroll
    for (int b = 0; b < 4; ++b) acc[a][b] = (f32x4){0.f, 0.f, 0.f, 0.f};
  for (int c = 0; c < 8; ++c) {
    __syncthreads();
    #pragma unroll
    for (int i = 0; i < 4; ++i) {
      *(short8*)(Ab + (i * 32 + srow) * 128 + dsw) = ra[i];
      *(short8*)(Bb + (i * 32 + srow) * 128 + dsw) = rb[i];
    }
    if (c < 7) {
      #pragma unroll
      for (int i = 0; i < 4; ++i) {
        ra[i] = *(const short8*)(asrc + i * 16384 + (c + 1) * 64);
        rb[i] = *(const short8*)(bsrc + i * 16384 + (c + 1) * 64);
      }
    }
    __syncthreads();
    #pragma unroll
    for (int ks = 0; ks < 2; ++ks) {
      const int so = (((ks << 2) | kg) ^ (lm & 7)) << 4;
      short8 af[4], bf[4];
      #pragma unroll
      for (int fr = 0; fr < 4; ++fr)
        af[fr] = *(const short8*)(Ab + (wr + fr * 16 + lm) * 128 + so);
      #pragma unroll
      for (int fc = 0; fc < 4; ++fc)
        bf[fc] = *(const short8*)(Bb + (wc + fc * 16 + lm) * 128 + so);
      #pragma unroll
      for (int fr = 0; fr < 4; ++fr)
        #pragma unroll
        for (int fc = 0; fc < 4; ++fc)
          acc[fr][fc] = __builtin_amdgcn_mfma_f32_16x16x32_bf16(af[fr], bf[fc], acc[fr][fc], 0, 0, 0);
    }
  }
  // epilogue: C row = kg*4+q, col = lm; pack lm-pairs to u32
  #pragma unroll
  for (int fr = 0; fr < 4; ++fr)
    #pragma unroll
    for (int fc = 0; fc < 4; ++fc)
      #pragma unroll
      for (int q = 0; q < 4; ++q) {
        int row = m0 + wr + fr * 16 + kg * 4 + q;
        int coln = n0 + wc + fc * 16 + lm;
        float v = acc[fr][fc][q];
        float vo = __shfl_xor(v, 1);
        if (!(lm & 1)) {
          unsigned int ud;
          asm("v_cvt_pk_bf16_f32 %0, %1, %2" : "=v"(ud) : "v"(v), "v"(vo));
          *(unsigned int*)(xg + (size_t)row * 1536 + coln) = ud;
        }
      }
}

// ---- level loop, one pass (cooperative): h-side GEMM + GRU epilogue ----
// grid = nrep*32 blocks x 512 thr (8 waves). block tile: 256 rows x 16 cols.
// LDS: A chunk [256][128B] swizzled (32KB) + U weights 3x16x512 (48KB) = 80KB.
template <int PASS>
__launch_bounds__(512, 4)
__global__ void tree_pass(const unsigned short* __restrict__ wt,
                          const unsigned short* __restrict__ xg,
                          unsigned short* __restrict__ Hs,
                          const unsigned short* __restrict__ zrow,
                          const float* __restrict__ bias,
                          const int* __restrict__ sched,
                          const int* __restrict__ meta,
                          const int* __restrict__ pslot,
                          const int* __restrict__ root_index,
                          float* __restrict__ out) {
  extern __shared__ unsigned char lds[];
  const int tid = threadIdx.x;
  const int bi = blockIdx.x;
  const int cg = bi & 31;
  const int rep = bi >> 5;
  const int nrep = gridDim.x >> 5;
  const int w = tid >> 6, l = tid & 63;
  const int lm = l & 15, kg = l >> 4;
  const int col = cg * 16 + lm;
  unsigned char* Ab = lds;
  unsigned char* Wb = lds + 32768;
  // stage U weights: [gate(3)][n16][512k], XOR-swizzled by n
  const unsigned short* wu = wt + (size_t)(PASS * 2 + 1) * (1536 * 512);
  for (int idx = tid; idx < 3072; idx += 512) {
    int k8 = idx & 63;
    int n = (idx >> 6) & 15;
    int g = idx >> 10;
    short8 v = *(const short8*)(wu + (size_t)(g * 512 + cg * 16 + n) * 512 + k8 * 8);
    *(short8*)(Wb + (g * 16 + n) * 1024 + ((k8 * 16) ^ ((n & 7) << 4))) = v;
  }
  const float br = bias[col], bz = bias[512 + col], bn = bias[1024 + col];
  const int srow = tid >> 3, sslot = tid & 7;
  const int dsw = ((sslot ^ (srow & 7)) << 4);
  cooperative_groups::grid_group grid = cooperative_groups::this_grid();
  __syncthreads();
  const int Dmax = meta[0];
  for (int p = 0; p <= Dmax; ++p) {
    const int d = PASS ? p : (Dmax - p);
    const int off_d = meta[1 + d];
    const int cnt_d = meta[257 + d];
    const int T = (cnt_d + 255) >> 8;
    for (int t = rep; t < T; t += nrep) {
      const int g0 = off_d + t * 256;
      const int rows = min(256, cnt_d - t * 256);
      // per-thread staging sources (rows i*64 + srow, 16B each, coalesced per row)
      const unsigned short* src[4];
      #pragma unroll
      for (int i = 0; i < 4; ++i) {
        int r = min(i * 64 + srow, rows - 1);
        int gg = g0 + r;
        if (PASS == 0) {
          src[i] = Hs + (size_t)gg * 512 + sslot * 8;
        } else {
          int ps = pslot[gg];
          src[i] = (ps >= 0 ? Hs + (size_t)ps * 512 : zrow) + sslot * 8;
        }
      }
      short8 ra[4];
      #pragma unroll
      for (int i = 0; i < 4; ++i) ra[i] = *(const short8*)(src[i]);
      f32x4 aR[2], aZ[2], aN[2];
      #pragma unroll
      for (int fr = 0; fr < 2; ++fr) {
        aR[fr] = (f32x4){0.f, 0.f, 0.f, 0.f};
        aZ[fr] = (f32x4){0.f, 0.f, 0.f, 0.f};
        aN[fr] = (f32x4){0.f, 0.f, 0.f, 0.f};
      }
      for (int c = 0; c < 8; ++c) {
        __syncthreads();               // all waves done reading previous chunk
        #pragma unroll
        for (int i = 0; i < 4; ++i)
          *(short8*)(Ab + (i * 64 + srow) * 128 + dsw) = ra[i];
        if (c < 7) {
          #pragma unroll
          for (int i = 0; i < 4; ++i) ra[i] = *(const short8*)(src[i] + (c + 1) * 64);
        }
        __syncthreads();               // chunk visible
        #pragma unroll
        for (int ks = 0; ks < 2; ++ks) {
          const int so = (((ks << 2) | kg) ^ (lm & 7)) << 4;
          short8 af[2], bf[3];
          #pragma unroll
          for (int fr = 0; fr < 2; ++fr)
            af[fr] = *(const short8*)(Ab + (w * 32 + fr * 16 + lm) * 128 + so);
          #pragma unroll
          for (int g = 0; g < 3; ++g)
            bf[g] = *(const short8*)(Wb + (g * 16 + lm) * 1024 +
                                     ((c * 128 + ks * 64 + kg * 16) ^ ((lm & 7) << 4)));
          #pragma unroll
          for (int fr = 0; fr < 2; ++fr) {
            aR[fr] = __builtin_amdgcn_mfma_f32_16x16x32_bf16(af[fr], bf[0], aR[fr], 0, 0, 0);
            aZ[fr] = __builtin_amdgcn_mfma_f32_16x16x32_bf16(af[fr], bf[1], aZ[fr], 0, 0, 0);
            aN[fr] = __builtin_amdgcn_mfma_f32_16x16x32_bf16(af[fr], bf[2], aN[fr], 0, 0, 0);
          }
        }
      }
      // GRU epilogue: frag row r = w*32 + fr*16 + kg*4 + q, col = lm
      #pragma unroll
      for (int fq = 0; fq < 8; ++fq) {
        const int fr = fq >> 2, q = fq & 3;
        const int r = w * 32 + fr * 16 + kg * 4 + q;
        if (r >= rows) continue;
        const int g = g0 + r;
        const int e = sched[g];
        const int bO = e >> 8, node = e & 255;
        const int ps = pslot[g];
        float xr = bf2f(xg[(size_t)g * 1536 + col]);
        float xz = bf2f(xg[(size_t)g * 1536 + 512 + col]);
        float xn = bf2f(xg[(size_t)g * 1536 + 1024 + col]);
        float hprev;
        if (PASS == 0) hprev = bf2f(Hs[(size_t)g * 512 + col]);
        else           hprev = (ps >= 0) ? bf2f(Hs[(size_t)ps * 512 + col]) : 0.f;
        float rr = 1.f / (1.f + __expf(-(xr + br + aR[fr][q])));
        float zz = 1.f / (1.f + __expf(-(xz + bz + aZ[fr][q])));
        float e2 = __expf(2.f * (xn + bn + rr * aN[fr][q]));
        float nn = (e2 - 1.f) / (e2 + 1.f);   // tanh
        float h = (1.f - zz) * nn + zz * hprev;
        out[((size_t)bO * NL + node) * 1024 + PASS * 512 + col] = h;
        float ho = __shfl_xor(h, 1);
        if (!(lm & 1)) {
          unsigned int ud;
          asm("v_cvt_pk_bf16_f32 %0, %1, %2" : "=v"(ud) : "v"(h), "v"(ho));
          if (PASS == 0) {
            if (ps >= 0) atom_pk_bf16(Hs + (size_t)ps * 512 + col, ud);
          } else {
            *(unsigned int*)(Hs + (size_t)g * 512 + col) = ud;
          }
        }
      }
    }
    grid.sync();
  }
  // output_t: root hidden concat (after final sync; DT half done in prior launch)
  if (PASS == 1 && bi < NB) {
    int b = bi, root = root_index[b];
    for (int c2 = tid; c2 < 1024; c2 += 512)
      out[(size_t)NB * NL * 1024 + (size_t)b * 1024 + c2] =
          out[((size_t)b * NL + root) * 1024 + c2];
  }
}

extern "C" void kernel_launch(void* const* d_in, const int* in_sizes, int n_in,
                              void* d_out, int out_size, void* d_ws, size_t ws_size,
                              hipStream_t stream) {
  (void)in_sizes; (void)n_in; (void)out_size; (void)ws_size;
  const float* emb      = (const float*)d_in[0];
  const int*   td_pidx  = (const int*)d_in[4];
  const float* td_pval  = (const float*)d_in[5];
  const int*   root_idx = (const int*)d_in[6];
  const float* dt_Wx    = (const float*)d_in[7];
  const float* dt_Uh    = (const float*)d_in[8];
  const float* dt_b     = (const float*)d_in[9];
  const float* td_Wx    = (const float*)d_in[10];
  const float* td_Uh    = (const float*)d_in[11];
  const float* td_b     = (const float*)d_in[12];
  float* out = (float*)d_out;

  unsigned short* wt   = (unsigned short*)d_ws;
  unsigned short* Xc   = wt + (size_t)4 * 1536 * 512;
  unsigned short* xg   = Xc + (size_t)NG * 512;
  unsigned short* Hs   = xg + (size_t)NG * 1536;
  unsigned short* zrow = Hs + (size_t)NG * 512;
  int* sched = (int*)(zrow + 512);
  int* meta  = sched + NG;
  int* gidx  = meta + 520;
  int* pslot = gidx + NG;

  (void)hipMemsetAsync(Hs, 0, ((size_t)NG * 512 + 512) * 2, stream);  // Hs + zrow
  prep_wt4<<<dim3(48, 16, 4), dim3(256), 0, stream>>>(dt_Wx, dt_Uh, td_Wx, td_Uh, wt);
  prep_sched<<<dim3(1), dim3(256), 0, stream>>>(td_pidx, td_pval, sched, meta, gidx, pslot);
  prep_xc<<<dim3(NG / 4), dim3(256), 0, stream>>>(emb, sched, Xc);

  (void)hipFuncSetAttribute((const void*)tree_pass<0>,
                            hipFuncAttributeMaxDynamicSharedMemorySize, 81920);
  (void)hipFuncSetAttribute((const void*)tree_pass<1>,
                            hipFuncAttributeMaxDynamicSharedMemorySize, 81920);
  int nb0 = 0, nb1 = 0;
  (void)hipOccupancyMaxActiveBlocksPerMultiprocessor(&nb0, (const void*)tree_pass<0>, 512, 81920);
  (void)hipOccupancyMaxActiveBlocksPerMultiprocessor(&nb1, (const void*)tree_pass<1>, 512, 81920);
  if (nb0 < 1) nb0 = 1;
  if (nb1 < 1) nb1 = 1;
  int grid0 = min(512, nb0 * 256) & ~31;   // multiple of 32 (cg groups)
  int grid1 = min(512, nb1 * 256) & ~31;
  if (grid0 < 32) grid0 = 32;
  if (grid1 < 32) grid1 = 32;

  // ---- DT pass ----
  gemm_xg<<<dim3(256, 12), dim3(256), 0, stream>>>(Xc, wt, xg);
  {
    void* args[] = { (void*)&wt, (void*)&xg, (void*)&Hs, (void*)&zrow, (void*)&dt_b,
                     (void*)&sched, (void*)&meta, (void*)&pslot, (void*)&root_idx, (void*)&out };
    (void)hipLaunchCooperativeKernel((const void*)tree_pass<0>, dim3(grid0), dim3(512),
                                     args, 81920u, stream);
  }
  // ---- TD pass (reuses xg buffer) ----
  gemm_xg<<<dim3(256, 12), dim3(256), 0, stream>>>(Xc, wt + (size_t)2 * 1536 * 512, xg);
  {
    void* args[] = { (void*)&wt, (void*)&xg, (void*)&Hs, (void*)&zrow, (void*)&td_b,
                     (void*)&sched, (void*)&meta, (void*)&pslot, (void*)&root_idx, (void*)&out };
    (void)hipLaunchCooperativeKernel((const void*)tree_pass<1>, dim3(grid1), dim3(512),
                                     args, 81920u, stream);
  }
}

// Round 6
// 1634.547 us; speedup vs baseline: 1.1975x; 1.1975x over previous
//
#include <hip/hip_runtime.h>
#include <hip/hip_cooperative_groups.h>

// Tree-GRU encoder, round 6: fused both-pass cooperative kernel (26 grid syncs),
// x-side and h-side MFMA both in the level loop (no xg materialization -> the
// recurrent working set Xc/Hdt/Htd (~100MB) stays LLC-resident), block-staged
// coalesced LDS A-tiles, non-temporal stores for the 129MB out buffer.
//
// Layout per block: pass(2) x rep(4) x colgroup(32 x 16 h-cols). 512 thr.
// LDS: weights Wx+Uh gate slices 98304 B + A-stage x 16KB + h 16KB = 131072 B.
// Tile: 128 rows x 16 cols, K=512 in 8 chunks of 64 (single-buffer LDS,
// register-prefetch next chunk).
//
// ws (~107 MB): wt bf16 4x[1536][512] | Xc bf16 [NG][512] | Hdt bf16 [NG][512]
//               | zrow bf16[512] | Htd bf16 [NG][512] | sched/meta/gidx/pslot

#define NL 256
#define NB 128
#define NH 512
#define NG (NB * NL)
#define WLDS 98304

typedef short short8 __attribute__((ext_vector_type(8)));
typedef float f32x4 __attribute__((ext_vector_type(4)));

__device__ __forceinline__ float bf2f(unsigned short u) {
  union { unsigned int i; float f; } c; c.i = ((unsigned int)u) << 16; return c.f;
}
__device__ __forceinline__ unsigned short f2bf(float f) {
  union { float f; unsigned int i; } c; c.f = f;
  return (unsigned short)((c.i + 0x7FFFu + ((c.i >> 16) & 1u)) >> 16);  // RNE
}
__device__ __forceinline__ short8 pk_bf16(f32x4 a, f32x4 b) {
  union { unsigned int u[4]; short8 s; } r;
  asm("v_cvt_pk_bf16_f32 %0, %1, %2" : "=v"(r.u[0]) : "v"(a[0]), "v"(a[1]));
  asm("v_cvt_pk_bf16_f32 %0, %1, %2" : "=v"(r.u[1]) : "v"(a[2]), "v"(a[3]));
  asm("v_cvt_pk_bf16_f32 %0, %1, %2" : "=v"(r.u[2]) : "v"(b[0]), "v"(b[1]));
  asm("v_cvt_pk_bf16_f32 %0, %1, %2" : "=v"(r.u[3]) : "v"(b[2]), "v"(b[3]));
  return r.s;
}
__device__ __forceinline__ void atom_pk_bf16(unsigned short* p, unsigned int ud) {
  asm volatile("global_atomic_pk_add_bf16 %0, %1, off" :: "v"((void*)p), "v"(ud) : "memory");
}

// ---- prep: 4 weight matrices [512][1536] f32 -> transposed [1536][512] bf16 ----
__global__ void prep_wt4(const float* __restrict__ w0, const float* __restrict__ w1,
                         const float* __restrict__ w2, const float* __restrict__ w3,
                         unsigned short* __restrict__ wt) {
  __shared__ float t[32][33];
  const float* w = blockIdx.z == 0 ? w0 : blockIdx.z == 1 ? w1 : blockIdx.z == 2 ? w2 : w3;
  unsigned short* dst = wt + (size_t)blockIdx.z * 1536 * 512;
  int n0 = blockIdx.x * 32, k0 = blockIdx.y * 32;
  int tx = threadIdx.x & 31, ty = threadIdx.x >> 5;
  #pragma unroll
  for (int i = 0; i < 4; ++i)
    t[ty + 8 * i][tx] = w[(size_t)(k0 + ty + 8 * i) * 1536 + n0 + tx];
  __syncthreads();
  #pragma unroll
  for (int i = 0; i < 4; ++i)
    dst[(size_t)(n0 + ty + 8 * i) * 512 + k0 + tx] = f2bf(t[tx][ty + 8 * i]);
}

// ---- prep: depths, level buckets, slots, parent slots (1 block, 256 thr) ----
__global__ void prep_sched(const int* __restrict__ td_pidx,
                           const float* __restrict__ td_pval,
                           int* __restrict__ sched, int* __restrict__ meta,
                           int* __restrict__ gidx, int* __restrict__ pslot) {
  __shared__ unsigned char dep[NB][NL];
  __shared__ unsigned short cnb[NB][256];
  __shared__ int cnt[256];
  __shared__ int off[257];
  __shared__ int dmax_s;
  const int tid = threadIdx.x;
  for (int j = tid; j < NB * 256; j += 256) ((unsigned short*)cnb)[j] = 0;
  if (tid == 0) dmax_s = 0;
  __syncthreads();
  if (tid < NB) {
    int b = tid, lmax = 0;
    for (int i = 0; i < NL; ++i) {
      float pv = td_pval[i * NB + b];
      int pi = td_pidx[i * NB + b];
      int d = (pv != 0.f) ? (int)dep[b][pi] + 1 : 0;   // head[i] < i
      dep[b][i] = (unsigned char)d;
      cnb[b][d]++;
      lmax = max(lmax, d);
    }
    atomicMax(&dmax_s, lmax);
  }
  __syncthreads();
  {
    int s = 0;
    for (int b = 0; b < NB; ++b) s += cnb[b][tid];
    cnt[tid] = s;
  }
  __syncthreads();
  if (tid == 0) {
    int s = 0;
    for (int d = 0; d < 256; ++d) { off[d] = s; s += cnt[d]; }
    off[256] = s;
  }
  __syncthreads();
  {
    int run = off[tid];
    for (int b = 0; b < NB; ++b) {
      int t = cnb[b][tid];
      cnb[b][tid] = (unsigned short)run;
      run += t;
    }
  }
  __syncthreads();
  if (tid < NB) {
    int b = tid;
    for (int i = 0; i < NL; ++i) {
      float pv = td_pval[i * NB + b];
      int pi = td_pidx[i * NB + b];
      int d = dep[b][i];
      int g = cnb[b][d]++;
      sched[g] = (b << 8) | i;
      gidx[b * NL + i] = g;
      pslot[g] = (pv != 0.f) ? gidx[b * NL + pi] : -1;
    }
  }
  if (tid == 0) meta[0] = dmax_s;
  __syncthreads();
  meta[1 + tid] = off[tid];
  meta[257 + tid] = cnt[tid];
}

// ---- prep: gather emb rows into slot order, f32 -> bf16 ----
__global__ void prep_xc(const float* __restrict__ emb, const int* __restrict__ sched,
                        unsigned short* __restrict__ Xc) {
  int g = blockIdx.x * 4 + (threadIdx.x >> 6);
  int lane = threadIdx.x & 63;
  int e = sched[g];
  int b = e >> 8, node = e & 255;
  const float* src = emb + ((size_t)node * NB + b) * 512 + lane * 8;
  f32x4 v0 = *(const f32x4*)src;
  f32x4 v1 = *(const f32x4*)(src + 4);
  *(short8*)(Xc + (size_t)g * 512 + lane * 8) = pk_bf16(v0, v1);
}

// ---- main fused cooperative kernel ----
// grid = 256 blocks (1/CU) x 512 thr (8 waves).
// bi: pass = bi>>7, rep = (bi>>5)&3, cg = bi&31. Wave w owns rows [w*16, +16).
__launch_bounds__(512, 2)
__global__ void tree_gru(const float* __restrict__ dt_b,
                         const float* __restrict__ td_b,
                         const unsigned short* __restrict__ wt,
                         const unsigned short* __restrict__ Xc,
                         unsigned short* __restrict__ Hdt,
                         unsigned short* __restrict__ Htd,
                         const unsigned short* __restrict__ zrow,
                         const int* __restrict__ sched,
                         const int* __restrict__ meta,
                         const int* __restrict__ pslot,
                         const int* __restrict__ root_index,
                         float* __restrict__ out) {
  extern __shared__ unsigned char lds[];
  const int tid = threadIdx.x;
  const int bi  = blockIdx.x;
  const int pass = bi >> 7;          // 0 = DT bottom-up, 1 = TD top-down
  const int rep  = (bi >> 5) & 3;
  const int cg   = bi & 31;
  const int w  = tid >> 6, l = tid & 63;
  const int lm = l & 15, kg = l >> 4;
  const int col = cg * 16 + lm;

  // stage weight slices: [mat(Wx,Uh)][gate(r,z,n)][n16][k512] bf16, XOR-swizzled
  for (int idx = tid; idx < 6144; idx += 512) {
    int k8  = idx & 63;
    int n   = (idx >> 6) & 15;
    int g   = (idx >> 10) % 3;
    int mat = idx / 3072;
    const unsigned short* src = wt + (size_t)(pass * 2 + mat) * (1536 * 512)
                                   + (size_t)(g * 512 + cg * 16 + n) * 512 + k8 * 8;
    short8 v = *(const short8*)src;
    int off = ((mat * 3 + g) * 16 + n) * 1024 + ((k8 * 16) ^ ((n & 7) << 4));
    *(short8*)(lds + off) = v;
  }
  unsigned char* Xb = lds + WLDS;            // 16 KB A-stage (x)
  unsigned char* Hb = lds + WLDS + 16384;    // 16 KB A-stage (h)
  __syncthreads();

  const float* bias = pass ? td_b : dt_b;
  const float br = bias[col], bz = bias[NH + col], bn = bias[2 * NH + col];
  const int base_wr = (0 * 16 + lm) * 1024;
  const int base_wz = (1 * 16 + lm) * 1024;
  const int base_wn = (2 * 16 + lm) * 1024;
  const int base_ur = (3 * 16 + lm) * 1024;
  const int base_uz = (4 * 16 + lm) * 1024;
  const int base_un = (5 * 16 + lm) * 1024;
  const int wswz = (lm & 7) << 4;

  const int srow = tid >> 3, sslot = tid & 7;          // stage: 64 rows x 8 slots
  const int dsw = ((sslot ^ (srow & 7)) << 4);         // (i*64+srow)&7 == srow&7

  cooperative_groups::grid_group grid = cooperative_groups::this_grid();
  const int Dmax = meta[0];

  for (int p = 0; p <= Dmax; ++p) {
    const int d = pass ? p : (Dmax - p);
    const int off_d = meta[1 + d];
    const int cnt_d = meta[257 + d];
    const int T = (cnt_d + 127) >> 7;
    for (int t = rep; t < T; t += 4) {
      const int g0 = off_d + t * 128;
      const int rows = min(128, cnt_d - t * 128);
      // staging sources: rows i*64+srow (clamped), 16B slot each — coalesced
      const unsigned short *sx[2], *sh[2];
      #pragma unroll
      for (int i = 0; i < 2; ++i) {
        int r = min(i * 64 + srow, rows - 1);
        int gg = g0 + r;
        sx[i] = Xc + (size_t)gg * 512 + sslot * 8;
        if (pass == 0) {
          sh[i] = Hdt + (size_t)gg * 512 + sslot * 8;
        } else {
          int ps = pslot[gg];
          sh[i] = (ps >= 0 ? Htd + (size_t)ps * 512 : zrow) + sslot * 8;
        }
      }
      short8 rx0 = *(const short8*)sx[0], rx1 = *(const short8*)sx[1];
      short8 rh0 = *(const short8*)sh[0], rh1 = *(const short8*)sh[1];
      f32x4 aR = {0,0,0,0}, aZ = {0,0,0,0}, aXN = {0,0,0,0}, aHN = {0,0,0,0};
      for (int c = 0; c < 8; ++c) {
        __syncthreads();                       // all waves done with prev chunk
        *(short8*)(Xb + (srow)      * 128 + dsw) = rx0;
        *(short8*)(Xb + (64 + srow) * 128 + dsw) = rx1;
        *(short8*)(Hb + (srow)      * 128 + dsw) = rh0;
        *(short8*)(Hb + (64 + srow) * 128 + dsw) = rh1;
        if (c < 7) {
          rx0 = *(const short8*)(sx[0] + (c + 1) * 64);
          rx1 = *(const short8*)(sx[1] + (c + 1) * 64);
          rh0 = *(const short8*)(sh[0] + (c + 1) * 64);
          rh1 = *(const short8*)(sh[1] + (c + 1) * 64);
        }
        __syncthreads();                       // chunk visible
        #pragma unroll
        for (int ks = 0; ks < 2; ++ks) {
          const int so = (((ks << 2) | kg) ^ (lm & 7)) << 4;
          const int arow = w * 16 + lm;        // (arow&7) == (lm&7)
          short8 ax = *(const short8*)(Xb + arow * 128 + so);
          short8 ah = *(const short8*)(Hb + arow * 128 + so);
          const int kb = (c * 128 + ks * 64 + kg * 16) ^ wswz;
          short8 bwr = *(const short8*)(lds + base_wr + kb);
          short8 bwz = *(const short8*)(lds + base_wz + kb);
          short8 bwn = *(const short8*)(lds + base_wn + kb);
          short8 bur = *(const short8*)(lds + base_ur + kb);
          short8 buz = *(const short8*)(lds + base_uz + kb);
          short8 bun = *(const short8*)(lds + base_un + kb);
          aR  = __builtin_amdgcn_mfma_f32_16x16x32_bf16(ax, bwr, aR, 0, 0, 0);
          aZ  = __builtin_amdgcn_mfma_f32_16x16x32_bf16(ax, bwz, aZ, 0, 0, 0);
          aXN = __builtin_amdgcn_mfma_f32_16x16x32_bf16(ax, bwn, aXN, 0, 0, 0);
          aR  = __builtin_amdgcn_mfma_f32_16x16x32_bf16(ah, bur, aR, 0, 0, 0);
          aZ  = __builtin_amdgcn_mfma_f32_16x16x32_bf16(ah, buz, aZ, 0, 0, 0);
          aHN = __builtin_amdgcn_mfma_f32_16x16x32_bf16(ah, bun, aHN, 0, 0, 0);
        }
      }
      // GRU epilogue: lane covers rows w*16 + kg*4 + q, col = cg*16+lm
      #pragma unroll
      for (int q = 0; q < 4; ++q) {
        const int r = w * 16 + kg * 4 + q;
        if (r >= rows) continue;
        const int g = g0 + r;
        const int e = sched[g];
        const int bO = e >> 8, node = e & 255;
        const int ps = pslot[g];
        float hprev;
        if (pass == 0) hprev = bf2f(Hdt[(size_t)g * 512 + col]);
        else           hprev = (ps >= 0) ? bf2f(Htd[(size_t)ps * 512 + col]) : 0.f;
        float rr = 1.f / (1.f + __expf(-(aR[q] + br)));
        float zz = 1.f / (1.f + __expf(-(aZ[q] + bz)));
        float e2 = __expf(2.f * (aXN[q] + bn + rr * aHN[q]));
        float nn = (e2 - 1.f) / (e2 + 1.f);    // tanh
        float h = (1.f - zz) * nn + zz * hprev;
        __builtin_nontemporal_store(h, &out[((size_t)bO * NL + node) * 1024 + pass * 512 + col]);
        float ho = __shfl_xor(h, 1);
        if (!(lm & 1)) {
          unsigned int ud;
          asm("v_cvt_pk_bf16_f32 %0, %1, %2" : "=v"(ud) : "v"(h), "v"(ho));
          if (pass == 0) {
            if (ps >= 0) atom_pk_bf16(Hdt + (size_t)ps * 512 + col, ud);
          } else {
            *(unsigned int*)(Htd + (size_t)g * 512 + col) = ud;
          }
        }
      }
    }
    grid.sync();
  }

  // output_t: root hidden concat
  if (bi < NB) {
    int b = bi, root = root_index[b];
    for (int c = tid; c < 1024; c += 512)
      out[(size_t)NB * NL * 1024 + (size_t)b * 1024 + c] =
          out[((size_t)b * NL + root) * 1024 + c];
  }
}

extern "C" void kernel_launch(void* const* d_in, const int* in_sizes, int n_in,
                              void* d_out, int out_size, void* d_ws, size_t ws_size,
                              hipStream_t stream) {
  (void)in_sizes; (void)n_in; (void)out_size; (void)ws_size;
  const float* emb      = (const float*)d_in[0];
  const int*   td_pidx  = (const int*)d_in[4];
  const float* td_pval  = (const float*)d_in[5];
  const int*   root_idx = (const int*)d_in[6];
  const float* dt_Wx    = (const float*)d_in[7];
  const float* dt_Uh    = (const float*)d_in[8];
  const float* dt_b     = (const float*)d_in[9];
  const float* td_Wx    = (const float*)d_in[10];
  const float* td_Uh    = (const float*)d_in[11];
  const float* td_b     = (const float*)d_in[12];
  float* out = (float*)d_out;

  unsigned short* wt   = (unsigned short*)d_ws;
  unsigned short* Xc   = wt + (size_t)4 * 1536 * 512;
  unsigned short* Hdt  = Xc + (size_t)NG * NH;
  unsigned short* zrow = Hdt + (size_t)NG * NH;
  unsigned short* Htd  = zrow + NH;
  int* sched = (int*)(Htd + (size_t)NG * NH);
  int* meta  = sched + NG;
  int* gidx  = meta + 520;
  int* pslot = gidx + NG;

  (void)hipMemsetAsync(Hdt, 0, ((size_t)NG * NH + NH) * 2, stream);  // Hdt + zrow
  prep_wt4<<<dim3(48, 16, 4), dim3(256), 0, stream>>>(dt_Wx, dt_Uh, td_Wx, td_Uh, wt);
  prep_sched<<<dim3(1), dim3(256), 0, stream>>>(td_pidx, td_pval, sched, meta, gidx, pslot);
  prep_xc<<<dim3(NG / 4), dim3(256), 0, stream>>>(emb, sched, Xc);

  (void)hipFuncSetAttribute((const void*)tree_gru,
                            hipFuncAttributeMaxDynamicSharedMemorySize, 131072);

  void* args[] = {
    (void*)&dt_b, (void*)&td_b, (void*)&wt, (void*)&Xc, (void*)&Hdt, (void*)&Htd,
    (void*)&zrow, (void*)&sched, (void*)&meta, (void*)&pslot, (void*)&root_idx, (void*)&out
  };
  (void)hipLaunchCooperativeKernel((const void*)tree_gru, dim3(256), dim3(512),
                                   args, 131072u, stream);
}